// Round 1
// baseline (2302.324 us; speedup 1.0000x reference)
//
#include <hip/hip_runtime.h>
#include <stdint.h>

typedef unsigned short u16;
typedef __bf16 bf16x8 __attribute__((ext_vector_type(8)));
typedef float f32x4 __attribute__((ext_vector_type(4)));

#define B_ 8
#define T_ 96
#define N_ 400
#define F_ 256
#define MROWS (B_*T_*N_)   // 307200
// bnt layout: row (b,n,t) = (b*400+n)*96 + t ; per-(b,n) tile = 96*256 = 24576 elems

__device__ __forceinline__ float bf2f(u16 u){
  union { uint32_t i; float f; } c; c.i = ((uint32_t)u) << 16; return c.f;
}
__device__ __forceinline__ u16 f2bf(float x){
  union { float f; uint32_t i; } c; c.f = x;
  uint32_t u = c.i;
  u = (u + 0x7FFFu + ((u >> 16) & 1u)) >> 16;
  return (u16)u;
}

__device__ __forceinline__ void gll16(const void* g, void* l){
  __builtin_amdgcn_global_load_lds((const __attribute__((address_space(1))) uint32_t*)g,
                                   (__attribute__((address_space(3))) uint32_t*)l, 16, 0, 0);
}

__device__ __forceinline__ f32x4 mfma16(bf16x8 a, bf16x8 b, f32x4 c){
  return __builtin_amdgcn_mfma_f32_16x16x32_bf16(a, b, c, 0, 0, 0);
}

// ---------------- weight convert fp32 -> bf16 ----------------
__global__ __launch_bounds__(256) void cvtw_k(const float* __restrict__ src, u16* __restrict__ dst){
  int i = (blockIdx.x * 256 + threadIdx.x) * 4;
  float4 v = *(const float4*)(src + i);
  union { u16 h[4]; uint2 u; } o;
  o.h[0] = f2bf(v.x); o.h[1] = f2bf(v.y); o.h[2] = f2bf(v.z); o.h[3] = f2bf(v.w);
  *(uint2*)(dst + i) = o.u;
}

// ---------------- prep: xl2/xh2 = bf16(x+te) in [b,n,t,f] order ----------------
__global__ __launch_bounds__(256) void prep_k(const float* __restrict__ xl, const float* __restrict__ xh,
                                              const float* __restrict__ te,
                                              u16* __restrict__ xl2, u16* __restrict__ xh2){
  long i0 = ((long)blockIdx.x * 256 + threadIdx.x) * 8;   // output (bnt) element index
  int row_o = (int)(i0 >> 8); int f = (int)(i0 & 255);
  int b = row_o / 38400; int r = row_o - b*38400; int n = r / 96; int t = r - n*96;
  long ioff = ((long)((b*96 + t)*400 + n))*256 + f;       // input (btn) element index
  long toff = ((long)(b*96 + t))*256 + f;
  float4 t0 = *(const float4*)(te + toff);
  float4 t1 = *(const float4*)(te + toff + 4);
  float4 a0 = *(const float4*)(xl + ioff), a1 = *(const float4*)(xl + ioff + 4);
  float4 b0 = *(const float4*)(xh + ioff), b1 = *(const float4*)(xh + ioff + 4);
  union { u16 h[8]; uint4 v; } oa, ob;
  oa.h[0]=f2bf(a0.x+t0.x); oa.h[1]=f2bf(a0.y+t0.y); oa.h[2]=f2bf(a0.z+t0.z); oa.h[3]=f2bf(a0.w+t0.w);
  oa.h[4]=f2bf(a1.x+t1.x); oa.h[5]=f2bf(a1.y+t1.y); oa.h[6]=f2bf(a1.z+t1.z); oa.h[7]=f2bf(a1.w+t1.w);
  ob.h[0]=f2bf(b0.x+t0.x); ob.h[1]=f2bf(b0.y+t0.y); ob.h[2]=f2bf(b0.z+t0.z); ob.h[3]=f2bf(b0.w+t0.w);
  ob.h[4]=f2bf(b1.x+t1.x); ob.h[5]=f2bf(b1.y+t1.y); ob.h[6]=f2bf(b1.z+t1.z); ob.h[7]=f2bf(b1.w+t1.w);
  *(uint4*)(xl2 + i0) = oa.v;
  *(uint4*)(xh2 + i0) = ob.v;
}

// ---------------- GEMM: C[m,o] = A[m,:] . W[o,:] + bias[o] ----------------
// tile 128 rows x 256 cols, 512 threads = 8 waves (2x4 grid of 64x64)
// TRANSV: write output transposed per (b,n): vbt[bn*24576 + col*96 + t]
// F32OUT (with LN): write fp32 to [b,t,n,f] order
template<bool RELU, bool LN, bool F32OUT, bool TRANSV>
__global__ __launch_bounds__(512, 1) void gemm_k(const u16* __restrict__ A, const u16* __restrict__ W,
                                                 const float* __restrict__ bias, const u16* __restrict__ Res,
                                                 void* __restrict__ Out){
  __shared__ u16 lds[128*32 + 256*32];  // 24 KB: A tile then B tile
  const int tid = threadIdx.x;
  const int w = tid >> 6, lane = tid & 63, quad = lane >> 4, l16 = lane & 15;
  const int rw = w & 1, cw = w >> 1;
  const long row0 = (long)blockIdx.x * 128;

  f32x4 acc[4][4];
  #pragma unroll
  for (int i=0;i<4;i++)
    #pragma unroll
    for (int j=0;j<4;j++) acc[i][j] = (f32x4)0.0f;

  for (int ks = 0; ks < 8; ++ks){
    __syncthreads();
    #pragma unroll
    for (int j = 0; j < 3; ++j){
      int c = j*512 + tid;
      const u16* src;
      if (c < 512){ int r = c >> 2, kc = c & 3; src = A + ((row0 + r)*256 + ks*32 + kc*8); }
      else        { int cb = c - 512; int o = cb >> 2, kc = cb & 3; src = W + (o*256 + ks*32 + kc*8); }
      u16* dst = lds + (j*512 + w*64)*8;   // wave-uniform base; HW adds lane*16B
      gll16(src, dst);
    }
    __syncthreads();
    bf16x8 af[4], bfp[4];
    #pragma unroll
    for (int rt=0;rt<4;rt++) af[rt]  = *(const bf16x8*)(lds + ((rw*64 + rt*16 + l16)*32 + quad*8));
    #pragma unroll
    for (int ct=0;ct<4;ct++) bfp[ct] = *(const bf16x8*)(lds + 4096 + ((cw*64 + ct*16 + l16)*32 + quad*8));
    #pragma unroll
    for (int rt=0;rt<4;rt++)
      #pragma unroll
      for (int ct=0;ct<4;ct++)
        acc[rt][ct] = mfma16(af[rt], bfp[ct], acc[rt][ct]);
  }

  float bb[4];
  #pragma unroll
  for (int ct=0;ct<4;ct++) bb[ct] = bias[cw*64 + ct*16 + l16];

  #pragma unroll
  for (int rt=0;rt<4;rt++){
    #pragma unroll
    for (int reg=0;reg<4;reg++){
      long grow = row0 + rw*64 + rt*16 + quad*4 + reg;
      #pragma unroll
      for (int ct=0;ct<4;ct++){
        float v = acc[rt][ct][reg] + bb[ct];
        if (RELU) v = fmaxf(v, 0.0f);
        if (LN)   v += bf2f(Res[grow*256 + cw*64 + ct*16 + l16]);
        acc[rt][ct][reg] = v;
      }
    }
  }

  if (!LN){
    if (TRANSV){
      // transposed V write: [bn][f][t], 4 regs = 4 consecutive t -> 8B packed store
      u16* o16 = (u16*)Out;
      #pragma unroll
      for (int rt=0;rt<4;rt++){
        int grow0 = (int)(row0 + rw*64 + rt*16 + quad*4);   // multiple of 4; 96%4==0 -> no bn crossing
        int bn = grow0 / 96; int t0 = grow0 - bn*96;
        u16* dstb = o16 + (long)bn*24576 + t0;
        #pragma unroll
        for (int ct=0;ct<4;ct++){
          union { u16 h[4]; uint2 u; } pk;
          #pragma unroll
          for (int reg=0;reg<4;reg++) pk.h[reg] = f2bf(acc[rt][ct][reg]);
          int col = cw*64 + ct*16 + l16;
          *(uint2*)(dstb + (long)col*96) = pk.u;
        }
      }
    } else {
      u16* o16 = (u16*)Out;
      #pragma unroll
      for (int rt=0;rt<4;rt++)
        #pragma unroll
        for (int reg=0;reg<4;reg++){
          long grow = row0 + rw*64 + rt*16 + quad*4 + reg;
          #pragma unroll
          for (int ct=0;ct<4;ct++)
            o16[grow*256 + cw*64 + ct*16 + l16] = f2bf(acc[rt][ct][reg]);
        }
    }
  } else {
    __syncthreads();
    float* red = (float*)lds;       // [128][4][2]
    float* mr  = red + 1024;        // [128][2]
    #pragma unroll
    for (int rt=0;rt<4;rt++){
      #pragma unroll
      for (int reg=0;reg<4;reg++){
        float s = 0.f, s2 = 0.f;
        #pragma unroll
        for (int ct=0;ct<4;ct++){ float v = acc[rt][ct][reg]; s += v; s2 += v*v; }
        #pragma unroll
        for (int m=1;m<16;m<<=1){ s += __shfl_xor(s, m); s2 += __shfl_xor(s2, m); }
        int rl = rw*64 + rt*16 + quad*4 + reg;
        if (l16 == 0){ red[(rl*4 + cw)*2] = s; red[(rl*4 + cw)*2 + 1] = s2; }
      }
    }
    __syncthreads();
    if (tid < 128){
      float s = 0.f, s2 = 0.f;
      #pragma unroll
      for (int i=0;i<4;i++){ s += red[(tid*4 + i)*2]; s2 += red[(tid*4 + i)*2 + 1]; }
      float mean = s * (1.0f/256.0f);
      float var  = s2 * (1.0f/256.0f) - mean*mean;
      mr[tid*2] = mean; mr[tid*2 + 1] = rsqrtf(var + 1e-5f);
    }
    __syncthreads();
    #pragma unroll
    for (int rt=0;rt<4;rt++){
      #pragma unroll
      for (int reg=0;reg<4;reg++){
        int rl = rw*64 + rt*16 + quad*4 + reg;
        long grow = row0 + rl;
        float mean = mr[rl*2], rs = mr[rl*2 + 1];
        #pragma unroll
        for (int ct=0;ct<4;ct++){
          float v = (acc[rt][ct][reg] - mean) * rs;
          if (F32OUT){
            // map bnt row -> btn fp32 output row
            int g = (int)grow; int b = g / 38400; int r = g - b*38400;
            int n = r / 96; int t = r - n*96;
            long orow = ((long)((b*96 + t)*400 + n))*256;
            ((float*)Out)[orow + cw*64 + ct*16 + l16] = v;
          } else {
            ((u16*)Out)[grow*256 + cw*64 + ct*16 + l16] = f2bf(v);
          }
        }
      }
    }
  }
}

// ---------------- attention: per (b,n) block; Q,K in [bn][t][f], V pre-transposed [bn][f][t] ----------------
// LDS: region A = 16384 u16 (32KB) staging (K halves / Vt halves), XOR-swizzled (chunk ^= row&7)
//      region P = 96*104 u16 P matrix (stride 104 breaks bank alignment)
__global__ __launch_bounds__(256, 3) void attn_k(const u16* __restrict__ Q, const u16* __restrict__ K,
                                                 const u16* __restrict__ V, u16* __restrict__ O){
  __shared__ u16 sm[16384 + 96*104];   // 52736 B -> 3 blocks/CU
  const int tid = threadIdx.x, w = tid >> 6, lane = tid & 63, quad = lane >> 4, l16 = lane & 15;
  const long base = (long)blockIdx.x * 24576;
  const int NT = (w < 2) ? 2 : 1;      // waves 0,1 own t-tiles {w,w+4}; waves 2,3 own {w}
  u16* smP = sm + 16384;

  // ---- issue K half 0 stage (f 0..127), swizzled source -> linear LDS ----
  #pragma unroll
  for (int it=0; it<6; ++it){
    int idx = it*256 + tid; int s = idx >> 4, c = idx & 15;
    gll16(K + base + s*256 + ((c ^ (s & 7)) * 8), sm + (it*256 + w*64)*8);
  }

  // Q fragments direct from global (contiguous 48KB tile, L2-hot)
  bf16x8 aq[2][8];
  for (int rt=0; rt<2; ++rt){
    if (rt < NT){
      int t = (w + rt*4)*16 + l16;
      const u16* qp = Q + base + t*256 + quad*8;
      #pragma unroll
      for (int kf=0;kf<8;kf++) aq[rt][kf] = *(const bf16x8*)(qp + kf*32);
    }
  }

  f32x4 accS[2][6];
  #pragma unroll
  for (int i=0;i<2;i++)
    #pragma unroll
    for (int j=0;j<6;j++) accS[i][j] = (f32x4)0.0f;

  // ---- phase 1: S = Q K^T over two f-halves ----
  for (int h=0; h<2; ++h){
    if (h){
      __syncthreads();
      #pragma unroll
      for (int it=0; it<6; ++it){
        int idx = it*256 + tid; int s = idx >> 4, c = idx & 15;
        gll16(K + base + s*256 + 128 + ((c ^ (s & 7)) * 8), sm + (it*256 + w*64)*8);
      }
    }
    __syncthreads();
    #pragma unroll
    for (int ks=0; ks<4; ++ks){
      bf16x8 bk[6];
      #pragma unroll
      for (int ct=0;ct<6;ct++){
        int s = ct*16 + l16;
        bk[ct] = *(const bf16x8*)(sm + s*128 + (((ks*4 + quad) ^ (s & 7))*8));
      }
      for (int rt=0; rt<NT; ++rt)
        #pragma unroll
        for (int ct=0;ct<6;ct++)
          accS[rt][ct] = mfma16(aq[rt][h*4 + ks], bk[ct], accS[rt][ct]);
    }
  }

  // ---- softmax (mask BEFORE scale, NEG=-32767), write P to LDS ----
  const float scale = 0.0625f;
  const float NEGs = -32767.0f * 0.0625f;
  for (int rt=0; rt<NT; ++rt){
    int tl = w + rt*4;
    #pragma unroll
    for (int reg=0;reg<4;reg++){
      int t = tl*16 + quad*4 + reg;
      float vals[6]; float m = -3.4e38f;
      #pragma unroll
      for (int ct=0;ct<6;ct++){
        int s = ct*16 + l16;
        float v = (s <= t) ? accS[rt][ct][reg]*scale : NEGs;
        vals[ct] = v; m = fmaxf(m, v);
      }
      #pragma unroll
      for (int msk=1;msk<16;msk<<=1) m = fmaxf(m, __shfl_xor(m, msk));
      float sum = 0.f;
      #pragma unroll
      for (int ct=0;ct<6;ct++){ float p = __expf(vals[ct] - m); vals[ct] = p; sum += p; }
      #pragma unroll
      for (int msk=1;msk<16;msk<<=1) sum += __shfl_xor(sum, msk);
      float inv = 1.0f / sum;
      #pragma unroll
      for (int ct=0;ct<6;ct++) smP[t*104 + ct*16 + l16] = f2bf(vals[ct]*inv);
    }
  }
  __syncthreads();

  // ---- phase 2: O = P Vt over two f-halves; Vt rows are t-contiguous ----
  // issue Vt half 0 stage (f-rows 0..127; 16 chunk slots, 12 valid, junk slots never read)
  #pragma unroll
  for (int it=0; it<8; ++it){
    int idx = it*256 + tid; int fr = idx >> 4, c = idx & 15;
    gll16(V + base + fr*96 + ((c ^ (fr & 7)) * 8), sm + (it*256 + w*64)*8);
  }
  // P fragments
  bf16x8 ap[2][3];
  for (int rt=0; rt<NT; ++rt){
    int t = (w + rt*4)*16 + l16;
    #pragma unroll
    for (int ks=0;ks<3;ks++) ap[rt][ks] = *(const bf16x8*)(smP + t*104 + ks*32 + quad*8);
  }

  for (int h=0; h<2; ++h){
    __syncthreads();
    f32x4 accO[2][8];
    #pragma unroll
    for (int i=0;i<2;i++)
      #pragma unroll
      for (int j=0;j<8;j++) accO[i][j] = (f32x4)0.0f;
    #pragma unroll
    for (int ks=0;ks<3;ks++){
      bf16x8 bv[8];
      #pragma unroll
      for (int ct=0;ct<8;ct++){
        int fr = ct*16 + l16;
        bv[ct] = *(const bf16x8*)(sm + fr*128 + (((ks*4 + quad) ^ (fr & 7))*8));
      }
      for (int rt=0; rt<NT; ++rt)
        #pragma unroll
        for (int ct=0;ct<8;ct++)
          accO[rt][ct] = mfma16(ap[rt][ks], bv[ct], accO[rt][ct]);
    }
    if (h == 0){
      __syncthreads();   // all waves done reading half-0 Vt
      #pragma unroll
      for (int it=0; it<8; ++it){
        int idx = it*256 + tid; int fr = idx >> 4, c = idx & 15;
        gll16(V + base + (128 + fr)*96 + ((c ^ (fr & 7)) * 8), sm + (it*256 + w*64)*8);
      }
    }
    // write O half h (overlaps with half-1 staging when h==0)
    for (int rt=0; rt<NT; ++rt){
      int tl = w + rt*4;
      #pragma unroll
      for (int reg=0;reg<4;reg++){
        int t = tl*16 + quad*4 + reg;
        long gb = base + t*256 + h*128;
        #pragma unroll
        for (int ct=0;ct<8;ct++) O[gb + ct*16 + l16] = f2bf(accO[rt][ct][reg]);
      }
    }
  }
}

extern "C" void kernel_launch(void* const* d_in, const int* in_sizes, int n_in,
                              void* d_out, int out_size, void* d_ws, size_t ws_size,
                              hipStream_t stream){
  const float* xl  = (const float*)d_in[0];
  const float* xh  = (const float*)d_in[1];
  const float* te  = (const float*)d_in[2];
  const float* Wq  = (const float*)d_in[3];  const float* bq  = (const float*)d_in[4];
  const float* Wk  = (const float*)d_in[5];  const float* bk  = (const float*)d_in[6];
  const float* Wv  = (const float*)d_in[7];  const float* bv  = (const float*)d_in[8];
  const float* Wo  = (const float*)d_in[9];  const float* bo  = (const float*)d_in[10];
  const float* Wf1 = (const float*)d_in[11]; const float* bf1 = (const float*)d_in[12];
  const float* Wf2 = (const float*)d_in[13]; const float* bf2 = (const float*)d_in[14];

  u16* ws = (u16*)d_ws;
  const long S1 = (long)MROWS * 256;
  u16* xl2 = ws;            // bf16(xl+te) in bnt, kept for Wo residual
  u16* xh2 = ws + S1;       // bf16(xh+te) in bnt; later reused as attention output
  u16* qb  = ws + 2*S1;     // q; later reused as out1
  u16* kb  = ws + 3*S1;     // k; later reused as h1
  u16* vb  = ws + 4*S1;     // v, stored transposed per (b,n): [bn][f][t]
  u16* wb  = ws + 5*S1;     // 6 bf16 weight matrices
  u16* wbq = wb, *wbk = wb + 65536, *wbv = wb + 2*65536,
     * wbo = wb + 3*65536, *wbf1 = wb + 4*65536, *wbf2 = wb + 5*65536;

  cvtw_k<<<64, 256, 0, stream>>>(Wq,  wbq);
  cvtw_k<<<64, 256, 0, stream>>>(Wk,  wbk);
  cvtw_k<<<64, 256, 0, stream>>>(Wv,  wbv);
  cvtw_k<<<64, 256, 0, stream>>>(Wo,  wbo);
  cvtw_k<<<64, 256, 0, stream>>>(Wf1, wbf1);
  cvtw_k<<<64, 256, 0, stream>>>(Wf2, wbf2);

  prep_k<<<38400, 256, 0, stream>>>(xl, xh, te, xl2, xh2);

  const int GB = MROWS / 128;  // 2400
  gemm_k<false,false,false,false><<<GB, 512, 0, stream>>>(xl2, wbq, bq, nullptr, qb);   // q
  gemm_k<true, false,false,false><<<GB, 512, 0, stream>>>(xh2, wbk, bk, nullptr, kb);   // k = relu
  gemm_k<true, false,false,true ><<<GB, 512, 0, stream>>>(xh2, wbv, bv, nullptr, vb);   // v = relu, transposed [bn][f][t]

  attn_k<<<B_*N_, 256, 0, stream>>>(qb, kb, vb, xh2);                                   // O -> xh2 slot (bnt)

  gemm_k<false,true, false,false><<<GB, 512, 0, stream>>>(xh2, wbo, bo, xl2, qb);       // out1 = LN(O.Wo+bo+xl2)
  gemm_k<true, false,false,false><<<GB, 512, 0, stream>>>(qb,  wbf1, bf1, nullptr, kb); // h1 = relu(...)
  gemm_k<false,true, true ,false><<<GB, 512, 0, stream>>>(kb,  wbf2, bf2, qb, d_out);   // LN(h1.Wf2+bf2+out1) -> fp32 btn
}

// Round 2
// 1609.338 us; speedup vs baseline: 1.4306x; 1.4306x over previous
//
#include <hip/hip_runtime.h>
#include <stdint.h>

typedef unsigned short u16;
typedef __bf16 bf16x8 __attribute__((ext_vector_type(8)));
typedef float f32x4 __attribute__((ext_vector_type(4)));

#define B_ 8
#define T_ 96
#define N_ 400
#define F_ 256
#define MROWS (B_*T_*N_)   // 307200
// bnt layout: row (b,n,t) = (b*400+n)*96 + t ; per-(b,n) tile = 96*256 = 24576 elems

__device__ __forceinline__ float bf2f(u16 u){
  union { uint32_t i; float f; } c; c.i = ((uint32_t)u) << 16; return c.f;
}
__device__ __forceinline__ u16 f2bf(float x){
  union { float f; uint32_t i; } c; c.f = x;
  uint32_t u = c.i;
  u = (u + 0x7FFFu + ((u >> 16) & 1u)) >> 16;
  return (u16)u;
}

__device__ __forceinline__ void gll16(const void* g, void* l){
  __builtin_amdgcn_global_load_lds((const __attribute__((address_space(1))) uint32_t*)g,
                                   (__attribute__((address_space(3))) uint32_t*)l, 16, 0, 0);
}

__device__ __forceinline__ f32x4 mfma16(bf16x8 a, bf16x8 b, f32x4 c){
  return __builtin_amdgcn_mfma_f32_16x16x32_bf16(a, b, c, 0, 0, 0);
}

// ---------------- weight convert fp32 -> bf16 ----------------
__global__ __launch_bounds__(256) void cvtw_k(const float* __restrict__ src, u16* __restrict__ dst){
  int i = (blockIdx.x * 256 + threadIdx.x) * 4;
  float4 v = *(const float4*)(src + i);
  union { u16 h[4]; uint2 u; } o;
  o.h[0] = f2bf(v.x); o.h[1] = f2bf(v.y); o.h[2] = f2bf(v.z); o.h[3] = f2bf(v.w);
  *(uint2*)(dst + i) = o.u;
}

// ---------------- prep: xl2/xh2 = bf16(x+te) in [b,n,t,f] order ----------------
__global__ __launch_bounds__(256) void prep_k(const float* __restrict__ xl, const float* __restrict__ xh,
                                              const float* __restrict__ te,
                                              u16* __restrict__ xl2, u16* __restrict__ xh2){
  long i0 = ((long)blockIdx.x * 256 + threadIdx.x) * 8;   // output (bnt) element index
  int row_o = (int)(i0 >> 8); int f = (int)(i0 & 255);
  int b = row_o / 38400; int r = row_o - b*38400; int n = r / 96; int t = r - n*96;
  long ioff = ((long)((b*96 + t)*400 + n))*256 + f;       // input (btn) element index
  long toff = ((long)(b*96 + t))*256 + f;
  float4 t0 = *(const float4*)(te + toff);
  float4 t1 = *(const float4*)(te + toff + 4);
  float4 a0 = *(const float4*)(xl + ioff), a1 = *(const float4*)(xl + ioff + 4);
  float4 b0 = *(const float4*)(xh + ioff), b1 = *(const float4*)(xh + ioff + 4);
  union { u16 h[8]; uint4 v; } oa, ob;
  oa.h[0]=f2bf(a0.x+t0.x); oa.h[1]=f2bf(a0.y+t0.y); oa.h[2]=f2bf(a0.z+t0.z); oa.h[3]=f2bf(a0.w+t0.w);
  oa.h[4]=f2bf(a1.x+t1.x); oa.h[5]=f2bf(a1.y+t1.y); oa.h[6]=f2bf(a1.z+t1.z); oa.h[7]=f2bf(a1.w+t1.w);
  ob.h[0]=f2bf(b0.x+t0.x); ob.h[1]=f2bf(b0.y+t0.y); ob.h[2]=f2bf(b0.z+t0.z); ob.h[3]=f2bf(b0.w+t0.w);
  ob.h[4]=f2bf(b1.x+t1.x); ob.h[5]=f2bf(b1.y+t1.y); ob.h[6]=f2bf(b1.z+t1.z); ob.h[7]=f2bf(b1.w+t1.w);
  *(uint4*)(xl2 + i0) = oa.v;
  *(uint4*)(xh2 + i0) = ob.v;
}

// ---------------- GEMM: C[m,o] = A[m,:] . W[o,:] + bias[o] ----------------
// tile 128 rows x 256 cols, 512 threads = 8 waves (2x4 grid of 64x64)
// TRANSV: write output transposed per (b,n): vbt[bn*24576 + col*96 + t]
// F32OUT (with LN): write fp32 to [b,t,n,f] order
template<bool RELU, bool LN, bool F32OUT, bool TRANSV>
__global__ __launch_bounds__(512, 1) void gemm_k(const u16* __restrict__ A, const u16* __restrict__ W,
                                                 const float* __restrict__ bias, const u16* __restrict__ Res,
                                                 void* __restrict__ Out){
  __shared__ u16 lds[128*32 + 256*32];  // 24 KB: A tile then B tile
  const int tid = threadIdx.x;
  const int w = tid >> 6, lane = tid & 63, quad = lane >> 4, l16 = lane & 15;
  const int rw = w & 1, cw = w >> 1;
  const long row0 = (long)blockIdx.x * 128;

  f32x4 acc[4][4];
  #pragma unroll
  for (int i=0;i<4;i++)
    #pragma unroll
    for (int j=0;j<4;j++) acc[i][j] = (f32x4)0.0f;

  for (int ks = 0; ks < 8; ++ks){
    __syncthreads();
    #pragma unroll
    for (int j = 0; j < 3; ++j){
      int c = j*512 + tid;
      const u16* src;
      if (c < 512){ int r = c >> 2, kc = c & 3; src = A + ((row0 + r)*256 + ks*32 + kc*8); }
      else        { int cb = c - 512; int o = cb >> 2, kc = cb & 3; src = W + (o*256 + ks*32 + kc*8); }
      u16* dst = lds + (j*512 + w*64)*8;   // wave-uniform base; HW adds lane*16B
      gll16(src, dst);
    }
    __syncthreads();
    bf16x8 af[4], bfp[4];
    #pragma unroll
    for (int rt=0;rt<4;rt++) af[rt]  = *(const bf16x8*)(lds + ((rw*64 + rt*16 + l16)*32 + quad*8));
    #pragma unroll
    for (int ct=0;ct<4;ct++) bfp[ct] = *(const bf16x8*)(lds + 4096 + ((cw*64 + ct*16 + l16)*32 + quad*8));
    #pragma unroll
    for (int rt=0;rt<4;rt++)
      #pragma unroll
      for (int ct=0;ct<4;ct++)
        acc[rt][ct] = mfma16(af[rt], bfp[ct], acc[rt][ct]);
  }

  float bb[4];
  #pragma unroll
  for (int ct=0;ct<4;ct++) bb[ct] = bias[cw*64 + ct*16 + l16];

  #pragma unroll
  for (int rt=0;rt<4;rt++){
    #pragma unroll
    for (int reg=0;reg<4;reg++){
      long grow = row0 + rw*64 + rt*16 + quad*4 + reg;
      #pragma unroll
      for (int ct=0;ct<4;ct++){
        float v = acc[rt][ct][reg] + bb[ct];
        if (RELU) v = fmaxf(v, 0.0f);
        if (LN)   v += bf2f(Res[grow*256 + cw*64 + ct*16 + l16]);
        acc[rt][ct][reg] = v;
      }
    }
  }

  if (!LN){
    if (TRANSV){
      // transposed V write: [bn][f][t], 4 regs = 4 consecutive t -> 8B packed store
      u16* o16 = (u16*)Out;
      #pragma unroll
      for (int rt=0;rt<4;rt++){
        int grow0 = (int)(row0 + rw*64 + rt*16 + quad*4);   // multiple of 4; 96%4==0 -> no bn crossing
        int bn = grow0 / 96; int t0 = grow0 - bn*96;
        u16* dstb = o16 + (long)bn*24576 + t0;
        #pragma unroll
        for (int ct=0;ct<4;ct++){
          union { u16 h[4]; uint2 u; } pk;
          #pragma unroll
          for (int reg=0;reg<4;reg++) pk.h[reg] = f2bf(acc[rt][ct][reg]);
          int col = cw*64 + ct*16 + l16;
          *(uint2*)(dstb + (long)col*96) = pk.u;
        }
      }
    } else {
      u16* o16 = (u16*)Out;
      #pragma unroll
      for (int rt=0;rt<4;rt++)
        #pragma unroll
        for (int reg=0;reg<4;reg++){
          long grow = row0 + rw*64 + rt*16 + quad*4 + reg;
          #pragma unroll
          for (int ct=0;ct<4;ct++)
            o16[grow*256 + cw*64 + ct*16 + l16] = f2bf(acc[rt][ct][reg]);
        }
    }
  } else {
    __syncthreads();
    float* red = (float*)lds;       // [128][4][2]
    float* mr  = red + 1024;        // [128][2]
    #pragma unroll
    for (int rt=0;rt<4;rt++){
      #pragma unroll
      for (int reg=0;reg<4;reg++){
        float s = 0.f, s2 = 0.f;
        #pragma unroll
        for (int ct=0;ct<4;ct++){ float v = acc[rt][ct][reg]; s += v; s2 += v*v; }
        #pragma unroll
        for (int m=1;m<16;m<<=1){ s += __shfl_xor(s, m); s2 += __shfl_xor(s2, m); }
        int rl = rw*64 + rt*16 + quad*4 + reg;
        if (l16 == 0){ red[(rl*4 + cw)*2] = s; red[(rl*4 + cw)*2 + 1] = s2; }
      }
    }
    __syncthreads();
    if (tid < 128){
      float s = 0.f, s2 = 0.f;
      #pragma unroll
      for (int i=0;i<4;i++){ s += red[(tid*4 + i)*2]; s2 += red[(tid*4 + i)*2 + 1]; }
      float mean = s * (1.0f/256.0f);
      float var  = s2 * (1.0f/256.0f) - mean*mean;
      mr[tid*2] = mean; mr[tid*2 + 1] = rsqrtf(var + 1e-5f);
    }
    __syncthreads();
    #pragma unroll
    for (int rt=0;rt<4;rt++){
      #pragma unroll
      for (int reg=0;reg<4;reg++){
        int rl = rw*64 + rt*16 + quad*4 + reg;
        long grow = row0 + rl;
        float mean = mr[rl*2], rs = mr[rl*2 + 1];
        #pragma unroll
        for (int ct=0;ct<4;ct++){
          float v = (acc[rt][ct][reg] - mean) * rs;
          if (F32OUT){
            // map bnt row -> btn fp32 output row
            int g = (int)grow; int b = g / 38400; int r = g - b*38400;
            int n = r / 96; int t = r - n*96;
            long orow = ((long)((b*96 + t)*400 + n))*256;
            ((float*)Out)[orow + cw*64 + ct*16 + l16] = v;
          } else {
            ((u16*)Out)[grow*256 + cw*64 + ct*16 + l16] = f2bf(v);
          }
        }
      }
    }
  }
}

// ---------------- attention: per (b,n) block; Q,K in [bn][t][f], V pre-transposed [bn][f][t] ----------------
// LDS: region A = 16384 u16 (32KB) staging (K halves / Vt halves), XOR-swizzled (chunk ^= row&7)
//      region P = 96*104 u16 P matrix (stride 104 breaks bank alignment)
// t-tiles (6 of 16 rows): waves 0,1 own {w, w+4}; waves 2,3 own {w} only.
// ALL loops over rt are compile-time bound (#pragma unroll) with wave-uniform
// `continue` guards -- runtime loop bounds here demote acc arrays to scratch (rule #20).
__global__ __launch_bounds__(256, 3) void attn_k(const u16* __restrict__ Q, const u16* __restrict__ K,
                                                 const u16* __restrict__ V, u16* __restrict__ O){
  __shared__ u16 sm[16384 + 96*104];   // 52736 B -> 3 blocks/CU
  const int tid = threadIdx.x, w = tid >> 6, lane = tid & 63, quad = lane >> 4, l16 = lane & 15;
  const long base = (long)blockIdx.x * 24576;
  const bool two = (w < 2);            // wave-uniform
  u16* smP = sm + 16384;

  // ---- issue K half 0 stage (f 0..127), swizzled source -> linear LDS ----
  #pragma unroll
  for (int it=0; it<6; ++it){
    int idx = it*256 + tid; int s = idx >> 4, c = idx & 15;
    gll16(K + base + s*256 + ((c ^ (s & 7)) * 8), sm + (it*256 + w*64)*8);
  }

  // Q fragments direct from global (contiguous 48KB tile, L2-hot)
  bf16x8 aq[2][8];
  #pragma unroll
  for (int rt=0; rt<2; ++rt){
    if (rt == 0 || two){
      int t = (w + rt*4)*16 + l16;
      const u16* qp = Q + base + t*256 + quad*8;
      #pragma unroll
      for (int kf=0;kf<8;kf++) aq[rt][kf] = *(const bf16x8*)(qp + kf*32);
    } else {
      #pragma unroll
      for (int kf=0;kf<8;kf++) aq[rt][kf] = (bf16x8)(__bf16)0.0f;
    }
  }

  f32x4 accS[2][6];
  #pragma unroll
  for (int i=0;i<2;i++)
    #pragma unroll
    for (int j=0;j<6;j++) accS[i][j] = (f32x4)0.0f;

  // ---- phase 1: S = Q K^T over two f-halves ----
  #pragma unroll
  for (int h=0; h<2; ++h){
    if (h){
      __syncthreads();
      #pragma unroll
      for (int it=0; it<6; ++it){
        int idx = it*256 + tid; int s = idx >> 4, c = idx & 15;
        gll16(K + base + s*256 + 128 + ((c ^ (s & 7)) * 8), sm + (it*256 + w*64)*8);
      }
    }
    __syncthreads();
    #pragma unroll
    for (int ks=0; ks<4; ++ks){
      bf16x8 bk[6];
      #pragma unroll
      for (int ct=0;ct<6;ct++){
        int s = ct*16 + l16;
        bk[ct] = *(const bf16x8*)(sm + s*128 + (((ks*4 + quad) ^ (s & 7))*8));
      }
      #pragma unroll
      for (int rt=0; rt<2; ++rt){
        if (rt == 1 && !two) continue;
        #pragma unroll
        for (int ct=0;ct<6;ct++)
          accS[rt][ct] = mfma16(aq[rt][h*4 + ks], bk[ct], accS[rt][ct]);
      }
    }
  }

  // ---- softmax (mask BEFORE scale, NEG=-32767), write P to LDS ----
  const float scale = 0.0625f;
  const float NEGs = -32767.0f * 0.0625f;
  #pragma unroll
  for (int rt=0; rt<2; ++rt){
    if (rt == 1 && !two) continue;
    int tl = w + rt*4;
    #pragma unroll
    for (int reg=0;reg<4;reg++){
      int t = tl*16 + quad*4 + reg;
      float vals[6]; float m = -3.4e38f;
      #pragma unroll
      for (int ct=0;ct<6;ct++){
        int s = ct*16 + l16;
        float v = (s <= t) ? accS[rt][ct][reg]*scale : NEGs;
        vals[ct] = v; m = fmaxf(m, v);
      }
      #pragma unroll
      for (int msk=1;msk<16;msk<<=1) m = fmaxf(m, __shfl_xor(m, msk));
      float sum = 0.f;
      #pragma unroll
      for (int ct=0;ct<6;ct++){ float p = __expf(vals[ct] - m); vals[ct] = p; sum += p; }
      #pragma unroll
      for (int msk=1;msk<16;msk<<=1) sum += __shfl_xor(sum, msk);
      float inv = 1.0f / sum;
      #pragma unroll
      for (int ct=0;ct<6;ct++) smP[t*104 + ct*16 + l16] = f2bf(vals[ct]*inv);
    }
  }
  __syncthreads();

  // ---- phase 2: O = P Vt over two f-halves; Vt rows are t-contiguous ----
  // issue Vt half 0 stage (f-rows 0..127; 16 chunk slots, 12 valid, junk slots never read)
  #pragma unroll
  for (int it=0; it<8; ++it){
    int idx = it*256 + tid; int fr = idx >> 4, c = idx & 15;
    gll16(V + base + fr*96 + ((c ^ (fr & 7)) * 8), sm + (it*256 + w*64)*8);
  }
  // P fragments
  bf16x8 ap[2][3];
  #pragma unroll
  for (int rt=0; rt<2; ++rt){
    if (rt == 0 || two){
      int t = (w + rt*4)*16 + l16;
      #pragma unroll
      for (int ks=0;ks<3;ks++) ap[rt][ks] = *(const bf16x8*)(smP + t*104 + ks*32 + quad*8);
    } else {
      #pragma unroll
      for (int ks=0;ks<3;ks++) ap[rt][ks] = (bf16x8)(__bf16)0.0f;
    }
  }

  #pragma unroll
  for (int h=0; h<2; ++h){
    __syncthreads();
    f32x4 accO[2][8];
    #pragma unroll
    for (int i=0;i<2;i++)
      #pragma unroll
      for (int j=0;j<8;j++) accO[i][j] = (f32x4)0.0f;
    #pragma unroll
    for (int ks=0;ks<3;ks++){
      bf16x8 bv[8];
      #pragma unroll
      for (int ct=0;ct<8;ct++){
        int fr = ct*16 + l16;
        bv[ct] = *(const bf16x8*)(sm + fr*128 + (((ks*4 + quad) ^ (fr & 7))*8));
      }
      #pragma unroll
      for (int rt=0; rt<2; ++rt){
        if (rt == 1 && !two) continue;
        #pragma unroll
        for (int ct=0;ct<8;ct++)
          accO[rt][ct] = mfma16(ap[rt][ks], bv[ct], accO[rt][ct]);
      }
    }
    if (h == 0){
      __syncthreads();   // all waves done reading half-0 Vt
      #pragma unroll
      for (int it=0; it<8; ++it){
        int idx = it*256 + tid; int fr = idx >> 4, c = idx & 15;
        gll16(V + base + (128 + fr)*96 + ((c ^ (fr & 7)) * 8), sm + (it*256 + w*64)*8);
      }
    }
    // write O half h (overlaps with half-1 staging when h==0)
    #pragma unroll
    for (int rt=0; rt<2; ++rt){
      if (rt == 1 && !two) continue;
      int tl = w + rt*4;
      #pragma unroll
      for (int reg=0;reg<4;reg++){
        int t = tl*16 + quad*4 + reg;
        long gb = base + t*256 + h*128;
        #pragma unroll
        for (int ct=0;ct<8;ct++) O[gb + ct*16 + l16] = f2bf(accO[rt][ct][reg]);
      }
    }
  }
}

extern "C" void kernel_launch(void* const* d_in, const int* in_sizes, int n_in,
                              void* d_out, int out_size, void* d_ws, size_t ws_size,
                              hipStream_t stream){
  const float* xl  = (const float*)d_in[0];
  const float* xh  = (const float*)d_in[1];
  const float* te  = (const float*)d_in[2];
  const float* Wq  = (const float*)d_in[3];  const float* bq  = (const float*)d_in[4];
  const float* Wk  = (const float*)d_in[5];  const float* bk  = (const float*)d_in[6];
  const float* Wv  = (const float*)d_in[7];  const float* bv  = (const float*)d_in[8];
  const float* Wo  = (const float*)d_in[9];  const float* bo  = (const float*)d_in[10];
  const float* Wf1 = (const float*)d_in[11]; const float* bf1 = (const float*)d_in[12];
  const float* Wf2 = (const float*)d_in[13]; const float* bf2 = (const float*)d_in[14];

  u16* ws = (u16*)d_ws;
  const long S1 = (long)MROWS * 256;
  u16* xl2 = ws;            // bf16(xl+te) in bnt, kept for Wo residual
  u16* xh2 = ws + S1;       // bf16(xh+te) in bnt; later reused as attention output
  u16* qb  = ws + 2*S1;     // q; later reused as out1
  u16* kb  = ws + 3*S1;     // k; later reused as h1
  u16* vb  = ws + 4*S1;     // v, stored transposed per (b,n): [bn][f][t]
  u16* wb  = ws + 5*S1;     // 6 bf16 weight matrices
  u16* wbq = wb, *wbk = wb + 65536, *wbv = wb + 2*65536,
     * wbo = wb + 3*65536, *wbf1 = wb + 4*65536, *wbf2 = wb + 5*65536;

  cvtw_k<<<64, 256, 0, stream>>>(Wq,  wbq);
  cvtw_k<<<64, 256, 0, stream>>>(Wk,  wbk);
  cvtw_k<<<64, 256, 0, stream>>>(Wv,  wbv);
  cvtw_k<<<64, 256, 0, stream>>>(Wo,  wbo);
  cvtw_k<<<64, 256, 0, stream>>>(Wf1, wbf1);
  cvtw_k<<<64, 256, 0, stream>>>(Wf2, wbf2);

  prep_k<<<38400, 256, 0, stream>>>(xl, xh, te, xl2, xh2);

  const int GB = MROWS / 128;  // 2400
  gemm_k<false,false,false,false><<<GB, 512, 0, stream>>>(xl2, wbq, bq, nullptr, qb);   // q
  gemm_k<true, false,false,false><<<GB, 512, 0, stream>>>(xh2, wbk, bk, nullptr, kb);   // k = relu
  gemm_k<true, false,false,true ><<<GB, 512, 0, stream>>>(xh2, wbv, bv, nullptr, vb);   // v = relu, transposed [bn][f][t]

  attn_k<<<B_*N_, 256, 0, stream>>>(qb, kb, vb, xh2);                                   // O -> xh2 slot (bnt)

  gemm_k<false,true, false,false><<<GB, 512, 0, stream>>>(xh2, wbo, bo, xl2, qb);       // out1 = LN(O.Wo+bo+xl2)
  gemm_k<true, false,false,false><<<GB, 512, 0, stream>>>(qb,  wbf1, bf1, nullptr, kb); // h1 = relu(...)
  gemm_k<false,true, true ,false><<<GB, 512, 0, stream>>>(kb,  wbf2, bf2, qb, d_out);   // LN(h1.Wf2+bf2+out1) -> fp32 btn
}

// Round 4
// 1579.475 us; speedup vs baseline: 1.4577x; 1.0189x over previous
//
#include <hip/hip_runtime.h>
#include <stdint.h>

typedef unsigned short u16;
typedef __bf16 bf16x8 __attribute__((ext_vector_type(8)));
typedef float f32x4 __attribute__((ext_vector_type(4)));

#define B_ 8
#define T_ 96
#define N_ 400
#define F_ 256
#define MROWS (B_*T_*N_)   // 307200
// bnt layout: row (b,n,t) = (b*400+n)*96 + t ; per-(b,n) tile = 96*256 = 24576 elems

__device__ __forceinline__ float bf2f(u16 u){
  union { uint32_t i; float f; } c; c.i = ((uint32_t)u) << 16; return c.f;
}
__device__ __forceinline__ u16 f2bf(float x){
  union { float f; uint32_t i; } c; c.f = x;
  uint32_t u = c.i;
  u = (u + 0x7FFFu + ((u >> 16) & 1u)) >> 16;
  return (u16)u;
}

__device__ __forceinline__ void gll16(const void* g, void* l){
  __builtin_amdgcn_global_load_lds((const __attribute__((address_space(1))) uint32_t*)g,
                                   (__attribute__((address_space(3))) uint32_t*)l, 16, 0, 0);
}

__device__ __forceinline__ f32x4 mfma16(bf16x8 a, bf16x8 b, f32x4 c){
  return __builtin_amdgcn_mfma_f32_16x16x32_bf16(a, b, c, 0, 0, 0);
}

// ---------------- weight convert fp32 -> bf16 ----------------
__global__ __launch_bounds__(256) void cvtw_k(const float* __restrict__ src, u16* __restrict__ dst){
  int i = (blockIdx.x * 256 + threadIdx.x) * 4;
  float4 v = *(const float4*)(src + i);
  union { u16 h[4]; uint2 u; } o;
  o.h[0] = f2bf(v.x); o.h[1] = f2bf(v.y); o.h[2] = f2bf(v.z); o.h[3] = f2bf(v.w);
  *(uint2*)(dst + i) = o.u;
}

// ---------------- prep: xl2/xh2 = bf16(x+te) in [b,n,t,f] order ----------------
__global__ __launch_bounds__(256) void prep_k(const float* __restrict__ xl, const float* __restrict__ xh,
                                              const float* __restrict__ te,
                                              u16* __restrict__ xl2, u16* __restrict__ xh2){
  long i0 = ((long)blockIdx.x * 256 + threadIdx.x) * 8;   // output (bnt) element index
  int row_o = (int)(i0 >> 8); int f = (int)(i0 & 255);
  int b = row_o / 38400; int r = row_o - b*38400; int n = r / 96; int t = r - n*96;
  long ioff = ((long)((b*96 + t)*400 + n))*256 + f;       // input (btn) element index
  long toff = ((long)(b*96 + t))*256 + f;
  float4 t0 = *(const float4*)(te + toff);
  float4 t1 = *(const float4*)(te + toff + 4);
  float4 a0 = *(const float4*)(xl + ioff), a1 = *(const float4*)(xl + ioff + 4);
  float4 b0 = *(const float4*)(xh + ioff), b1 = *(const float4*)(xh + ioff + 4);
  union { u16 h[8]; uint4 v; } oa, ob;
  oa.h[0]=f2bf(a0.x+t0.x); oa.h[1]=f2bf(a0.y+t0.y); oa.h[2]=f2bf(a0.z+t0.z); oa.h[3]=f2bf(a0.w+t0.w);
  oa.h[4]=f2bf(a1.x+t1.x); oa.h[5]=f2bf(a1.y+t1.y); oa.h[6]=f2bf(a1.z+t1.z); oa.h[7]=f2bf(a1.w+t1.w);
  ob.h[0]=f2bf(b0.x+t0.x); ob.h[1]=f2bf(b0.y+t0.y); ob.h[2]=f2bf(b0.z+t0.z); ob.h[3]=f2bf(b0.w+t0.w);
  ob.h[4]=f2bf(b1.x+t1.x); ob.h[5]=f2bf(b1.y+t1.y); ob.h[6]=f2bf(b1.z+t1.z); ob.h[7]=f2bf(b1.w+t1.w);
  *(uint4*)(xl2 + i0) = oa.v;
  *(uint4*)(xh2 + i0) = ob.v;
}

// ---------------- GEMM: C[m,o] = A[m,:] . W[o,:] + bias[o] ----------------
// tile 128 rows x 256 cols, 512 threads = 8 waves (2x4 grid of 64x64)
// Double-buffered LDS (T3-minimum recipe): prologue stage; per K-step
// { STAGE(next) ; ds_read+MFMA(cur) ; one barrier }. Chunk-XOR swizzle
// (kc ^= row&3) on global source + LDS read (linear gll16 dest, rule #21)
// cuts ds_read_b128 bank conflicts 8-way -> 4-way.
// TRANSV: write output transposed per (b,n): vbt[bn*24576 + col*96 + t]
// F32OUT (with LN): write fp32 to [b,t,n,f] order
template<bool RELU, bool LN, bool F32OUT, bool TRANSV>
__global__ __launch_bounds__(512, 1) void gemm_k(const u16* __restrict__ A, const u16* __restrict__ W,
                                                 const float* __restrict__ bias, const u16* __restrict__ Res,
                                                 void* __restrict__ Out){
  __shared__ u16 lds[2*12288];  // 48 KB: per buffer, A tile (4096 u16) then W tile (8192 u16)
  const int tid = threadIdx.x;
  const int w = tid >> 6, lane = tid & 63, quad = lane >> 4, l16 = lane & 15;
  const int rw = w & 1, cw = w >> 1;
  const int swz8 = (quad ^ (l16 & 3)) * 8;     // lane-constant swizzled chunk offset
  const long row0 = (long)blockIdx.x * 128;

  f32x4 acc[4][4];
  #pragma unroll
  for (int i=0;i<4;i++)
    #pragma unroll
    for (int j=0;j<4;j++) acc[i][j] = (f32x4)0.0f;

  // staging: thread c stages 16B chunk c of buffer p for K-step ks.
  // j=0: A tile rows r=c>>2, chunk kc=c&3 (source chunk kc^(r&3))
  // j=1,2: W tile rows o, chunk kc (source chunk kc^(o&3))
  #define STAGE(p, ks)                                                                   \
    { _Pragma("unroll")                                                                  \
      for (int j = 0; j < 3; ++j){                                                       \
        int c = j*512 + tid;                                                             \
        const u16* src;                                                                  \
        if (c < 512){ int r = c >> 2, kc = c & 3;                                        \
                      src = A + ((row0 + r)*256 + (ks)*32 + ((kc ^ (r & 3))*8)); }       \
        else        { int cb = c - 512; int o = cb >> 2, kc = cb & 3;                    \
                      src = W + (o*256 + (ks)*32 + ((kc ^ (o & 3))*8)); }                \
        gll16(src, lds + (p)*12288 + (j*512 + w*64)*8);                                  \
      } }

  STAGE(0, 0);
  __syncthreads();

  #pragma unroll
  for (int ks = 0; ks < 8; ++ks){
    const int cur = ks & 1;
    if (ks < 7) STAGE(cur ^ 1, ks + 1);          // loads fly while we compute cur
    const u16* buf = lds + cur*12288;
    bf16x8 af[4], bfp[4];
    #pragma unroll
    for (int rt=0;rt<4;rt++){ int r = rw*64 + rt*16 + l16; af[rt]  = *(const bf16x8*)(buf + r*32 + swz8); }
    #pragma unroll
    for (int ct=0;ct<4;ct++){ int o = cw*64 + ct*16 + l16; bfp[ct] = *(const bf16x8*)(buf + 4096 + o*32 + swz8); }
    #pragma unroll
    for (int rt=0;rt<4;rt++)
      #pragma unroll
      for (int ct=0;ct<4;ct++)
        acc[rt][ct] = mfma16(af[rt], bfp[ct], acc[rt][ct]);
    __syncthreads();                             // drains staged loads + protects cur for overwrite
  }
  #undef STAGE

  float bb[4];
  #pragma unroll
  for (int ct=0;ct<4;ct++) bb[ct] = bias[cw*64 + ct*16 + l16];

  #pragma unroll
  for (int rt=0;rt<4;rt++){
    #pragma unroll
    for (int reg=0;reg<4;reg++){
      long grow = row0 + rw*64 + rt*16 + quad*4 + reg;
      #pragma unroll
      for (int ct=0;ct<4;ct++){
        float v = acc[rt][ct][reg] + bb[ct];
        if (RELU) v = fmaxf(v, 0.0f);
        if (LN)   v += bf2f(Res[grow*256 + cw*64 + ct*16 + l16]);
        acc[rt][ct][reg] = v;
      }
    }
  }

  if (!LN){
    if (TRANSV){
      // transposed V write: [bn][f][t], 4 regs = 4 consecutive t -> 8B packed store
      u16* o16 = (u16*)Out;
      #pragma unroll
      for (int rt=0;rt<4;rt++){
        int grow0 = (int)(row0 + rw*64 + rt*16 + quad*4);   // multiple of 4; 96%4==0 -> no bn crossing
        int bn = grow0 / 96; int t0 = grow0 - bn*96;
        u16* dstb = o16 + (long)bn*24576 + t0;
        #pragma unroll
        for (int ct=0;ct<4;ct++){
          union { u16 h[4]; uint2 u; } pk;
          #pragma unroll
          for (int reg=0;reg<4;reg++) pk.h[reg] = f2bf(acc[rt][ct][reg]);
          int col = cw*64 + ct*16 + l16;
          *(uint2*)(dstb + (long)col*96) = pk.u;
        }
      }
    } else {
      u16* o16 = (u16*)Out;
      #pragma unroll
      for (int rt=0;rt<4;rt++)
        #pragma unroll
        for (int reg=0;reg<4;reg++){
          long grow = row0 + rw*64 + rt*16 + quad*4 + reg;
          #pragma unroll
          for (int ct=0;ct<4;ct++)
            o16[grow*256 + cw*64 + ct*16 + l16] = f2bf(acc[rt][ct][reg]);
        }
    }
  } else {
    __syncthreads();
    float* red = (float*)lds;       // [128][4][2]
    float* mr  = red + 1024;        // [128][2]
    #pragma unroll
    for (int rt=0;rt<4;rt++){
      #pragma unroll
      for (int reg=0;reg<4;reg++){
        float s = 0.f, s2 = 0.f;
        #pragma unroll
        for (int ct=0;ct<4;ct++){ float v = acc[rt][ct][reg]; s += v; s2 += v*v; }
        #pragma unroll
        for (int m=1;m<16;m<<=1){ s += __shfl_xor(s, m); s2 += __shfl_xor(s2, m); }
        int rl = rw*64 + rt*16 + quad*4 + reg;
        if (l16 == 0){ red[(rl*4 + cw)*2] = s; red[(rl*4 + cw)*2 + 1] = s2; }
      }
    }
    __syncthreads();
    if (tid < 128){
      float s = 0.f, s2 = 0.f;
      #pragma unroll
      for (int i=0;i<4;i++){ s += red[(tid*4 + i)*2]; s2 += red[(tid*4 + i)*2 + 1]; }
      float mean = s * (1.0f/256.0f);
      float var  = s2 * (1.0f/256.0f) - mean*mean;
      mr[tid*2] = mean; mr[tid*2 + 1] = rsqrtf(var + 1e-5f);
    }
    __syncthreads();
    #pragma unroll
    for (int rt=0;rt<4;rt++){
      #pragma unroll
      for (int reg=0;reg<4;reg++){
        int rl = rw*64 + rt*16 + quad*4 + reg;
        long grow = row0 + rl;
        float mean = mr[rl*2], rs = mr[rl*2 + 1];
        #pragma unroll
        for (int ct=0;ct<4;ct++){
          float v = (acc[rt][ct][reg] - mean) * rs;
          if (F32OUT){
            // map bnt row -> btn fp32 output row
            int g = (int)grow; int b = g / 38400; int r = g - b*38400;
            int n = r / 96; int t = r - n*96;
            long orow = ((long)((b*96 + t)*400 + n))*256;
            ((float*)Out)[orow + cw*64 + ct*16 + l16] = v;
          } else {
            ((u16*)Out)[grow*256 + cw*64 + ct*16 + l16] = f2bf(v);
          }
        }
      }
    }
  }
}

// ---------------- attention: per (b,n) block; Q,K in [bn][t][f], V pre-transposed [bn][f][t] ----------------
// LDS: region A = 16384 u16 (32KB) staging (K halves / Vt halves), XOR-swizzled (chunk ^= row&7)
//      region P = 96*104 u16 P matrix (stride 104 breaks bank alignment)
// t-tiles (6 of 16 rows): waves 0,1 own {w, w+4}; waves 2,3 own {w} only.
// ALL loops over rt are compile-time bound (#pragma unroll) with wave-uniform
// `continue` guards -- runtime loop bounds here demote acc arrays to scratch (rule #20).
__global__ __launch_bounds__(256, 3) void attn_k(const u16* __restrict__ Q, const u16* __restrict__ K,
                                                 const u16* __restrict__ V, u16* __restrict__ O){
  __shared__ u16 sm[16384 + 96*104];   // 52736 B -> 3 blocks/CU
  const int tid = threadIdx.x, w = tid >> 6, lane = tid & 63, quad = lane >> 4, l16 = lane & 15;
  const long base = (long)blockIdx.x * 24576;
  const bool two = (w < 2);            // wave-uniform
  u16* smP = sm + 16384;

  // ---- issue K half 0 stage (f 0..127), swizzled source -> linear LDS ----
  #pragma unroll
  for (int it=0; it<6; ++it){
    int idx = it*256 + tid; int s = idx >> 4, c = idx & 15;
    gll16(K + base + s*256 + ((c ^ (s & 7)) * 8), sm + (it*256 + w*64)*8);
  }

  // Q fragments direct from global (contiguous 48KB tile, L2-hot)
  bf16x8 aq[2][8];
  #pragma unroll
  for (int rt=0; rt<2; ++rt){
    if (rt == 0 || two){
      int t = (w + rt*4)*16 + l16;
      const u16* qp = Q + base + t*256 + quad*8;
      #pragma unroll
      for (int kf=0;kf<8;kf++) aq[rt][kf] = *(const bf16x8*)(qp + kf*32);
    } else {
      #pragma unroll
      for (int kf=0;kf<8;kf++) aq[rt][kf] = (bf16x8)(__bf16)0.0f;
    }
  }

  f32x4 accS[2][6];
  #pragma unroll
  for (int i=0;i<2;i++)
    #pragma unroll
    for (int j=0;j<6;j++) accS[i][j] = (f32x4)0.0f;

  // ---- phase 1: S = Q K^T over two f-halves ----
  #pragma unroll
  for (int h=0; h<2; ++h){
    if (h){
      __syncthreads();
      #pragma unroll
      for (int it=0; it<6; ++it){
        int idx = it*256 + tid; int s = idx >> 4, c = idx & 15;
        gll16(K + base + s*256 + 128 + ((c ^ (s & 7)) * 8), sm + (it*256 + w*64)*8);
      }
    }
    __syncthreads();
    #pragma unroll
    for (int ks=0; ks<4; ++ks){
      bf16x8 bk[6];
      #pragma unroll
      for (int ct=0;ct<6;ct++){
        int s = ct*16 + l16;
        bk[ct] = *(const bf16x8*)(sm + s*128 + (((ks*4 + quad) ^ (s & 7))*8));
      }
      #pragma unroll
      for (int rt=0; rt<2; ++rt){
        if (rt == 1 && !two) continue;
        #pragma unroll
        for (int ct=0;ct<6;ct++)
          accS[rt][ct] = mfma16(aq[rt][h*4 + ks], bk[ct], accS[rt][ct]);
      }
    }
  }

  // ---- softmax (mask BEFORE scale, NEG=-32767), write P to LDS ----
  const float scale = 0.0625f;
  const float NEGs = -32767.0f * 0.0625f;
  #pragma unroll
  for (int rt=0; rt<2; ++rt){
    if (rt == 1 && !two) continue;
    int tl = w + rt*4;
    #pragma unroll
    for (int reg=0;reg<4;reg++){
      int t = tl*16 + quad*4 + reg;
      float vals[6]; float m = -3.4e38f;
      #pragma unroll
      for (int ct=0;ct<6;ct++){
        int s = ct*16 + l16;
        float v = (s <= t) ? accS[rt][ct][reg]*scale : NEGs;
        vals[ct] = v; m = fmaxf(m, v);
      }
      #pragma unroll
      for (int msk=1;msk<16;msk<<=1) m = fmaxf(m, __shfl_xor(m, msk));
      float sum = 0.f;
      #pragma unroll
      for (int ct=0;ct<6;ct++){ float p = __expf(vals[ct] - m); vals[ct] = p; sum += p; }
      #pragma unroll
      for (int msk=1;msk<16;msk<<=1) sum += __shfl_xor(sum, msk);
      float inv = 1.0f / sum;
      #pragma unroll
      for (int ct=0;ct<6;ct++) smP[t*104 + ct*16 + l16] = f2bf(vals[ct]*inv);
    }
  }
  __syncthreads();

  // ---- phase 2: O = P Vt over two f-halves; Vt rows are t-contiguous ----
  // issue Vt half 0 stage (f-rows 0..127; 16 chunk slots, 12 valid, junk slots never read)
  #pragma unroll
  for (int it=0; it<8; ++it){
    int idx = it*256 + tid; int fr = idx >> 4, c = idx & 15;
    gll16(V + base + fr*96 + ((c ^ (fr & 7)) * 8), sm + (it*256 + w*64)*8);
  }
  // P fragments
  bf16x8 ap[2][3];
  #pragma unroll
  for (int rt=0; rt<2; ++rt){
    if (rt == 0 || two){
      int t = (w + rt*4)*16 + l16;
      #pragma unroll
      for (int ks=0;ks<3;ks++) ap[rt][ks] = *(const bf16x8*)(smP + t*104 + ks*32 + quad*8);
    } else {
      #pragma unroll
      for (int ks=0;ks<3;ks++) ap[rt][ks] = (bf16x8)(__bf16)0.0f;
    }
  }

  #pragma unroll
  for (int h=0; h<2; ++h){
    __syncthreads();
    f32x4 accO[2][8];
    #pragma unroll
    for (int i=0;i<2;i++)
      #pragma unroll
      for (int j=0;j<8;j++) accO[i][j] = (f32x4)0.0f;
    #pragma unroll
    for (int ks=0;ks<3;ks++){
      bf16x8 bv[8];
      #pragma unroll
      for (int ct=0;ct<8;ct++){
        int fr = ct*16 + l16;
        bv[ct] = *(const bf16x8*)(sm + fr*128 + (((ks*4 + quad) ^ (fr & 7))*8));
      }
      #pragma unroll
      for (int rt=0; rt<2; ++rt){
        if (rt == 1 && !two) continue;
        #pragma unroll
        for (int ct=0;ct<8;ct++)
          accO[rt][ct] = mfma16(ap[rt][ks], bv[ct], accO[rt][ct]);
      }
    }
    if (h == 0){
      __syncthreads();   // all waves done reading half-0 Vt
      #pragma unroll
      for (int it=0; it<8; ++it){
        int idx = it*256 + tid; int fr = idx >> 4, c = idx & 15;
        gll16(V + base + (128 + fr)*96 + ((c ^ (fr & 7)) * 8), sm + (it*256 + w*64)*8);
      }
    }
    // write O half h (overlaps with half-1 staging when h==0)
    #pragma unroll
    for (int rt=0; rt<2; ++rt){
      if (rt == 1 && !two) continue;
      int tl = w + rt*4;
      #pragma unroll
      for (int reg=0;reg<4;reg++){
        int t = tl*16 + quad*4 + reg;
        long gb = base + t*256 + h*128;
        #pragma unroll
        for (int ct=0;ct<8;ct++) O[gb + ct*16 + l16] = f2bf(accO[rt][ct][reg]);
      }
    }
  }
}

extern "C" void kernel_launch(void* const* d_in, const int* in_sizes, int n_in,
                              void* d_out, int out_size, void* d_ws, size_t ws_size,
                              hipStream_t stream){
  const float* xl  = (const float*)d_in[0];
  const float* xh  = (const float*)d_in[1];
  const float* te  = (const float*)d_in[2];
  const float* Wq  = (const float*)d_in[3];  const float* bq  = (const float*)d_in[4];
  const float* Wk  = (const float*)d_in[5];  const float* bk  = (const float*)d_in[6];
  const float* Wv  = (const float*)d_in[7];  const float* bv  = (const float*)d_in[8];
  const float* Wo  = (const float*)d_in[9];  const float* bo  = (const float*)d_in[10];
  const float* Wf1 = (const float*)d_in[11]; const float* bf1 = (const float*)d_in[12];
  const float* Wf2 = (const float*)d_in[13]; const float* bf2 = (const float*)d_in[14];

  u16* ws = (u16*)d_ws;
  const long S1 = (long)MROWS * 256;
  u16* xl2 = ws;            // bf16(xl+te) in bnt, kept for Wo residual
  u16* xh2 = ws + S1;       // bf16(xh+te) in bnt; later reused as attention output
  u16* qb  = ws + 2*S1;     // q; later reused as out1
  u16* kb  = ws + 3*S1;     // k; later reused as h1
  u16* vb  = ws + 4*S1;     // v, stored transposed per (b,n): [bn][f][t]
  u16* wb  = ws + 5*S1;     // 6 bf16 weight matrices
  u16* wbq = wb, *wbk = wb + 65536, *wbv = wb + 2*65536,
     * wbo = wb + 3*65536, *wbf1 = wb + 4*65536, *wbf2 = wb + 5*65536;

  cvtw_k<<<64, 256, 0, stream>>>(Wq,  wbq);
  cvtw_k<<<64, 256, 0, stream>>>(Wk,  wbk);
  cvtw_k<<<64, 256, 0, stream>>>(Wv,  wbv);
  cvtw_k<<<64, 256, 0, stream>>>(Wo,  wbo);
  cvtw_k<<<64, 256, 0, stream>>>(Wf1, wbf1);
  cvtw_k<<<64, 256, 0, stream>>>(Wf2, wbf2);

  prep_k<<<38400, 256, 0, stream>>>(xl, xh, te, xl2, xh2);

  const int GB = MROWS / 128;  // 2400
  gemm_k<false,false,false,false><<<GB, 512, 0, stream>>>(xl2, wbq, bq, nullptr, qb);   // q
  gemm_k<true, false,false,false><<<GB, 512, 0, stream>>>(xh2, wbk, bk, nullptr, kb);   // k = relu
  gemm_k<true, false,false,true ><<<GB, 512, 0, stream>>>(xh2, wbv, bv, nullptr, vb);   // v = relu, transposed [bn][f][t]

  attn_k<<<B_*N_, 256, 0, stream>>>(qb, kb, vb, xh2);                                   // O -> xh2 slot (bnt)

  gemm_k<false,true, false,false><<<GB, 512, 0, stream>>>(xh2, wbo, bo, xl2, qb);       // out1 = LN(O.Wo+bo+xl2)
  gemm_k<true, false,false,false><<<GB, 512, 0, stream>>>(qb,  wbf1, bf1, nullptr, kb); // h1 = relu(...)
  gemm_k<false,true, true ,false><<<GB, 512, 0, stream>>>(kb,  wbf2, bf2, qb, d_out);   // LN(h1.Wf2+bf2+out1) -> fp32 btn
}